// Round 6
// baseline (990.246 us; speedup 1.0000x reference)
//
#include <hip/hip_runtime.h>
#include <hip/hip_cooperative_groups.h>

namespace cg = cooperative_groups;

// ---------------------------------------------------------------------------
// CapsuleSequenceToGraph, fp32 in/out. B=64, T={128,512,256,256}, n=32, d=16.
// Identity: b_k[b,t,n] = <Vcum_k[b,n,:], pri[b,t,n,:]>, Vcum_k = sum_{i<k} v_i.
// pri_kernel (MFMA) writes pri bf16; cooperative route_kernel runs all 4
// softmax-weighted-sum passes with grid.sync(). If the coop launch is
// rejected, a 9-dispatch fallback chain (same device code) runs instead.
//
// pri ws layout (bf16), per mod: [t][b][n*16+d]  (row = 512 shorts = 1KB)
// ws (bytes):
//   [0, 75497472)              pri bf16
//   [75497472, +524288)        S    fp32 [mod][b][n*16+d]
//   [76021760, +524288)        Vcum fp32 same layout
// ---------------------------------------------------------------------------

typedef __attribute__((ext_vector_type(8))) short short8;
typedef __attribute__((ext_vector_type(4))) float floatx4;

#define PRI_BYTES 75497472ull
#define S_ELEMS 131072

static __device__ __forceinline__ unsigned short f2bf(float f) {
  union { float f; unsigned int i; } v;
  v.f = f;
  unsigned int x = v.i;
  return (unsigned short)((x + 0x7fffu + ((x >> 16) & 1u)) >> 16);  // RNE
}

// ---------------------------------------------------------------------------
// pri = x @ W per t, bf16 MFMA 16x16x32. Block = (t, 16-n half): M=64(b) x
// N=256(nd) x K=64(j). LDS 36KB -> 4 blocks/CU (deeper memory pipeline for
// the latency-limited W stream). Blocks 0..255 also zero S+Vcum.
// ---------------------------------------------------------------------------
__global__ __launch_bounds__(256) void pri_kernel(
    const float* __restrict__ x0, const float* __restrict__ x1,
    const float* __restrict__ x2, const float* __restrict__ x3,
    const float* __restrict__ w0, const float* __restrict__ w1,
    const float* __restrict__ w2, const float* __restrict__ w3,
    unsigned short* __restrict__ priAll, float* __restrict__ SV) {
  __shared__ unsigned short wb[256 * 72];  // [nd_local][j] bf16, pitch 72

  int blk = blockIdx.x;
  int tid = threadIdx.x;

  if (blk < 256) {  // zero S and Vcum (2*131072 floats contiguous)
    int i = blk * 1024 + tid * 4;
    floatx4 z = {0.f, 0.f, 0.f, 0.f};
    *(floatx4*)(SV + i) = z;
  }

  int tpair = blk >> 1, half = blk & 1;
  const float* x;
  const float* W;
  unsigned short* priT;
  int T, t;
  if (tpair < 128)      { x = x0; W = w0; priT = priAll;               T = 128; t = tpair; }
  else if (tpair < 640) { x = x1; W = w1; priT = priAll + 4194304ull;  T = 512; t = tpair - 128; }
  else if (tpair < 896) { x = x2; W = w2; priT = priAll + 20971520ull; T = 256; t = tpair - 640; }
  else                  { x = x3; W = w3; priT = priAll + 29360128ull; T = 256; t = tpair - 896; }
  priT += (size_t)t * 32768;

  // ---- stage W[t, half*16 .. +16, :, :] -> wb[nd_local][j] bf16 ----
  {
    const floatx4* Wf4 = (const floatx4*)(W + (size_t)t * 32768);
    unsigned int* wb32 = (unsigned int*)wb;  // pitch 36 dwords
#pragma unroll
    for (int it = 0; it < 8; ++it) {
      int idx = it * 256 + tid;              // 0..2047
      int nl = idx >> 7, jp = (idx >> 2) & 31, dq = idx & 3;
      int ng = half * 16 + nl;
      floatx4 fa = Wf4[ng * 256 + (2 * jp) * 4 + dq];
      floatx4 fb = Wf4[ng * 256 + (2 * jp + 1) * 4 + dq];
      int rbase = nl * 16 + dq * 4;
#pragma unroll
      for (int k = 0; k < 4; ++k) {
        unsigned int dw = (unsigned int)f2bf(fa[k]) | ((unsigned int)f2bf(fb[k]) << 16);
        wb32[(rbase + k) * 36 + jp] = dw;
      }
    }
  }

  // ---- A fragments: x[b = mt*16+m][k = s*32 + q*8 + i] -> bf16 ----
  int lane = tid & 63, mt = tid >> 6;
  int m = lane & 15, q = lane >> 4;
  short8 afrag[2];
  {
    const float* xrow = x + ((size_t)(mt * 16 + m) * T + t) * 64;
#pragma unroll
    for (int s = 0; s < 2; ++s) {
      const floatx4* xp = (const floatx4*)(xrow + s * 32 + q * 8);
      floatx4 u0 = xp[0], u1 = xp[1];
      afrag[s][0] = (short)f2bf(u0[0]); afrag[s][1] = (short)f2bf(u0[1]);
      afrag[s][2] = (short)f2bf(u0[2]); afrag[s][3] = (short)f2bf(u0[3]);
      afrag[s][4] = (short)f2bf(u1[0]); afrag[s][5] = (short)f2bf(u1[1]);
      afrag[s][6] = (short)f2bf(u1[2]); afrag[s][7] = (short)f2bf(u1[3]);
    }
  }
  __syncthreads();

  // ---- 16 N-tiles; D layout: row b = mt*16+q*4+reg, col nd = nt*16+m ----
  unsigned short* pbase = priT + (size_t)(mt * 16 + q * 4) * 512 + half * 256 + m;
#pragma unroll 4
  for (int nt = 0; nt < 16; ++nt) {
    const short8* b0p = (const short8*)&wb[(nt * 16 + m) * 72 + q * 8];
    const short8* b1p = (const short8*)&wb[(nt * 16 + m) * 72 + 32 + q * 8];
    short8 bf0 = *b0p, bf1 = *b1p;
    floatx4 acc = {0.f, 0.f, 0.f, 0.f};
    acc = __builtin_amdgcn_mfma_f32_16x16x32_bf16(afrag[0], bf0, acc, 0, 0, 0);
    acc = __builtin_amdgcn_mfma_f32_16x16x32_bf16(afrag[1], bf1, acc, 0, 0, 0);
    unsigned short* pt = pbase + nt * 16;
    pt[0]    = f2bf(acc[0]);
    pt[512]  = f2bf(acc[1]);
    pt[1024] = f2bf(acc[2]);
    pt[1536] = f2bf(acc[3]);
  }
}

// ---------------------------------------------------------------------------
// Routing phase A (shared by coop + fallback): block = (b, 128-t slice).
// 8 groups of 32 lanes; lane = n; group g serially handles 16 t's (prefetch).
// Reduces into LDS then atomically into global S.
// ---------------------------------------------------------------------------
static __device__ __forceinline__ void route_decode(int blk, int& mod, int& b,
                                                    int& sl, size_t& poff) {
  b = blk / 9;
  int s = blk % 9;
  if (s == 0)      { mod = 0; sl = 0; poff = 0; }
  else if (s < 5)  { mod = 1; sl = s - 1; poff = 4194304ull; }
  else if (s < 7)  { mod = 2; sl = s - 5; poff = 20971520ull; }
  else             { mod = 3; sl = s - 7; poff = 29360128ull; }
}

static __device__ __forceinline__ void phaseA(
    const unsigned short* __restrict__ priAll, const float* __restrict__ Vcum,
    float* __restrict__ S, float* Sl, int blk, int tid) {
  int mod, b, sl;
  size_t poff;
  route_decode(blk, mod, b, sl, poff);

  int n = tid & 31, g = tid >> 5;

  Sl[tid] = 0.f;
  Sl[tid + 256] = 0.f;
  if (tid < 32) Sl[tid + 512] = 0.f;

  float Vc[16];
  {
    const floatx4* vp =
        (const floatx4*)(Vcum + (size_t)mod * 32768 + (size_t)b * 512 + n * 16);
    floatx4 v0 = vp[0], v1 = vp[1], v2 = vp[2], v3 = vp[3];
#pragma unroll
    for (int k = 0; k < 4; ++k) {
      Vc[k] = v0[k]; Vc[4 + k] = v1[k]; Vc[8 + k] = v2[k]; Vc[12 + k] = v3[k];
    }
  }
  __syncthreads();

  float acc[16];
#pragma unroll
  for (int d = 0; d < 16; ++d) acc[d] = 0.f;

  const unsigned short* pb = priAll + poff + (size_t)(sl * 128) * 32768
                             + (size_t)b * 512 + (size_t)n * 16;
  const uint4* q0 = (const uint4*)(pb + (size_t)g * 32768);
  uint4 c0 = q0[0], c1 = q0[1];
  for (int k = 0; k < 16; ++k) {
    uint4 n0, n1;
    if (k < 15) {
      const uint4* qn = (const uint4*)(pb + (size_t)(g + 8 * (k + 1)) * 32768);
      n0 = qn[0];
      n1 = qn[1];
    }
    float p[16];
    {
      unsigned int wds[8] = {c0.x, c0.y, c0.z, c0.w, c1.x, c1.y, c1.z, c1.w};
#pragma unroll
      for (int kk = 0; kk < 8; ++kk) {
        union { unsigned int u; float f; } lo, hi;
        lo.u = wds[kk] << 16;
        hi.u = wds[kk] & 0xffff0000u;
        p[2 * kk] = lo.f;
        p[2 * kk + 1] = hi.f;
      }
    }
    float logit = 0.f;
#pragma unroll
    for (int d = 0; d < 16; ++d) logit += p[d] * Vc[d];
    float mx = logit;
#pragma unroll
    for (int o = 16; o >= 1; o >>= 1) mx = fmaxf(mx, __shfl_xor(mx, o, 32));
    float e = __expf(logit - mx);
    float s = e;
#pragma unroll
    for (int o = 16; o >= 1; o >>= 1) s += __shfl_xor(s, o, 32);
    float rc = e / s;
#pragma unroll
    for (int d = 0; d < 16; ++d) acc[d] += rc * p[d];
    c0 = n0;
    c1 = n1;
  }

#pragma unroll
  for (int d = 0; d < 16; ++d) atomicAdd(&Sl[n * 17 + d], acc[d]);
  __syncthreads();

  float* srow = S + (size_t)mod * 32768 + (size_t)b * 512;
#pragma unroll
  for (int h = 0; h < 2; ++h) {
    int c = tid + h * 256;
    atomicAdd(&srow[c], Sl[(c >> 4) * 17 + (c & 15)]);
  }
}

// Cooperative: 576 blocks (<= 3/CU guaranteed by launch bounds), 4 passes.
__global__ __launch_bounds__(256, 3) void route_kernel(
    const unsigned short* __restrict__ priAll, float* __restrict__ S,
    float* __restrict__ Vcum, float* __restrict__ out) {
  cg::grid_group grid = cg::this_grid();
  __shared__ float Sl[544];
  int blk = blockIdx.x, tid = threadIdx.x;

  for (int pass = 0; pass < 4; ++pass) {
    phaseA(priAll, Vcum, S, Sl, blk, tid);
    __threadfence();
    grid.sync();

    if (blk < 512) {
      int i = blk * 256 + tid;
      float v = tanhf(S[i]);
      if (pass == 3) {
        out[i] = v;
      } else {
        Vcum[i] += v;
        S[i] = 0.f;
      }
    }
    if (pass < 3) {
      __threadfence();
      grid.sync();
    }
  }
}

// Fallback chain (used only if the cooperative launch is rejected).
__global__ __launch_bounds__(256) void pass_fb_kernel(
    const unsigned short* __restrict__ priAll, const float* __restrict__ Vcum,
    float* __restrict__ S) {
  __shared__ float Sl[544];
  phaseA(priAll, Vcum, S, Sl, blockIdx.x, threadIdx.x);
}

__global__ __launch_bounds__(256) void update_fb_kernel(
    float* __restrict__ S, float* __restrict__ Vcum, float* __restrict__ out,
    int final_) {
  int i = blockIdx.x * 256 + threadIdx.x;
  float v = tanhf(S[i]);
  if (final_) out[i] = v;
  else { Vcum[i] += v; S[i] = 0.f; }
}

extern "C" void kernel_launch(void* const* d_in, const int* in_sizes, int n_in,
                              void* d_out, int out_size, void* d_ws, size_t ws_size,
                              hipStream_t stream) {
  const float* x0 = (const float*)d_in[0];
  const float* x1 = (const float*)d_in[1];
  const float* x2 = (const float*)d_in[2];
  const float* x3 = (const float*)d_in[3];
  const float* w0 = (const float*)d_in[4];
  const float* w1 = (const float*)d_in[5];
  const float* w2 = (const float*)d_in[6];
  const float* w3 = (const float*)d_in[7];

  unsigned short* pri = (unsigned short*)d_ws;
  float* S = (float*)((char*)d_ws + PRI_BYTES);
  float* Vcum = S + S_ELEMS;
  float* out = (float*)d_out;

  pri_kernel<<<2304, 256, 0, stream>>>(x0, x1, x2, x3, w0, w1, w2, w3, pri, S);

  void* args[] = {(void*)&pri, (void*)&S, (void*)&Vcum, (void*)&out};
  hipError_t e = hipLaunchCooperativeKernel((const void*)route_kernel, dim3(576),
                                            dim3(256), args, 0, stream);
  if (e != hipSuccess) {
    // coop rejected (e.g. co-residency) -> equivalent multi-dispatch chain
    for (int p = 0; p < 4; ++p) {
      pass_fb_kernel<<<576, 256, 0, stream>>>(pri, Vcum, S);
      update_fb_kernel<<<512, 256, 0, stream>>>(S, Vcum, out, p == 3 ? 1 : 0);
    }
  }
}

// Round 7
// 321.538 us; speedup vs baseline: 3.0797x; 3.0797x over previous
//
#include <hip/hip_runtime.h>

// ---------------------------------------------------------------------------
// CapsuleSequenceToGraph, fp32 in/out. B=64, T={128,512,256,256}, n=32, d=16.
// Identity: b_k[b,t,n] = <Vcum_k[b,n,:], pri[b,t,n,:]>, Vcum_k = sum_{i<k} v_i.
//
// Structure (2 dispatches, no cross-block dependencies inside routing):
//   pri_kernel: bf16 MFMA, writes pri b-major [mod][b][t][n*16+d].
//   route_kernel: one block per (mod,b), 1024 threads, runs ALL 4 routing
//     passes block-locally (__syncthreads only; Vcum + S in LDS).
// Lessons baked in: dependent dispatch ~25us each (R2-R4); grid.sync ~115us
// per barrier on 8-XCD MI355X (R6) -> both eliminated.
//
// ws: [0, 75497472) pri bf16 only.
// ---------------------------------------------------------------------------

typedef __attribute__((ext_vector_type(8))) short short8;
typedef __attribute__((ext_vector_type(4))) float floatx4;

static __device__ __forceinline__ unsigned short f2bf(float f) {
  union { float f; unsigned int i; } v;
  v.f = f;
  unsigned int x = v.i;
  return (unsigned short)((x + 0x7fffu + ((x >> 16) & 1u)) >> 16);  // RNE
}

// ---------------------------------------------------------------------------
// pri = x @ W per t, bf16 MFMA 16x16x32. Block = (t, 16-n half): M=64(b) x
// N=256(nd) x K=64(j). LDS 36KB -> 4 blocks/CU.
// ---------------------------------------------------------------------------
__global__ __launch_bounds__(256) void pri_kernel(
    const float* __restrict__ x0, const float* __restrict__ x1,
    const float* __restrict__ x2, const float* __restrict__ x3,
    const float* __restrict__ w0, const float* __restrict__ w1,
    const float* __restrict__ w2, const float* __restrict__ w3,
    unsigned short* __restrict__ priAll) {
  __shared__ unsigned short wb[256 * 72];  // [nd_local][j] bf16, pitch 72

  int blk = blockIdx.x;
  int tid = threadIdx.x;

  int tpair = blk >> 1, half = blk & 1;
  const float* x;
  const float* W;
  unsigned short* priM;
  int T, t;
  if (tpair < 128)      { x = x0; W = w0; priM = priAll;               T = 128; t = tpair; }
  else if (tpair < 640) { x = x1; W = w1; priM = priAll + 4194304ull;  T = 512; t = tpair - 128; }
  else if (tpair < 896) { x = x2; W = w2; priM = priAll + 20971520ull; T = 256; t = tpair - 640; }
  else                  { x = x3; W = w3; priM = priAll + 29360128ull; T = 256; t = tpair - 896; }

  // ---- stage W[t, half*16 .. +16, :, :] -> wb[nd_local][j] bf16 ----
  {
    const floatx4* Wf4 = (const floatx4*)(W + (size_t)t * 32768);
    unsigned int* wb32 = (unsigned int*)wb;  // pitch 36 dwords
#pragma unroll
    for (int it = 0; it < 8; ++it) {
      int idx = it * 256 + tid;              // 0..2047
      int nl = idx >> 7, jp = (idx >> 2) & 31, dq = idx & 3;
      int ng = half * 16 + nl;
      floatx4 fa = Wf4[ng * 256 + (2 * jp) * 4 + dq];
      floatx4 fb = Wf4[ng * 256 + (2 * jp + 1) * 4 + dq];
      int rbase = nl * 16 + dq * 4;
#pragma unroll
      for (int k = 0; k < 4; ++k) {
        unsigned int dw = (unsigned int)f2bf(fa[k]) | ((unsigned int)f2bf(fb[k]) << 16);
        wb32[(rbase + k) * 36 + jp] = dw;
      }
    }
  }

  // ---- A fragments: x[b = mt*16+m][k = s*32 + q*8 + i] -> bf16 ----
  int lane = tid & 63, mt = tid >> 6;
  int m = lane & 15, q = lane >> 4;
  short8 afrag[2];
  {
    const float* xrow = x + ((size_t)(mt * 16 + m) * T + t) * 64;
#pragma unroll
    for (int s = 0; s < 2; ++s) {
      const floatx4* xp = (const floatx4*)(xrow + s * 32 + q * 8);
      floatx4 u0 = xp[0], u1 = xp[1];
      afrag[s][0] = (short)f2bf(u0[0]); afrag[s][1] = (short)f2bf(u0[1]);
      afrag[s][2] = (short)f2bf(u0[2]); afrag[s][3] = (short)f2bf(u0[3]);
      afrag[s][4] = (short)f2bf(u1[0]); afrag[s][5] = (short)f2bf(u1[1]);
      afrag[s][6] = (short)f2bf(u1[2]); afrag[s][7] = (short)f2bf(u1[3]);
    }
  }
  __syncthreads();

  // ---- 16 N-tiles; D layout: row b = mt*16+q*4+reg, col nd = nt*16+m ----
  // b-major store: addr = (b*T + t)*512 + half*256 + nt*16 + m
  size_t ts = (size_t)T * 512;  // reg stride (b -> b+1)
  unsigned short* pbase = priM + ((size_t)(mt * 16 + q * 4) * T + t) * 512 + half * 256 + m;
#pragma unroll 4
  for (int nt = 0; nt < 16; ++nt) {
    const short8* b0p = (const short8*)&wb[(nt * 16 + m) * 72 + q * 8];
    const short8* b1p = (const short8*)&wb[(nt * 16 + m) * 72 + 32 + q * 8];
    short8 bf0 = *b0p, bf1 = *b1p;
    floatx4 acc = {0.f, 0.f, 0.f, 0.f};
    acc = __builtin_amdgcn_mfma_f32_16x16x32_bf16(afrag[0], bf0, acc, 0, 0, 0);
    acc = __builtin_amdgcn_mfma_f32_16x16x32_bf16(afrag[1], bf1, acc, 0, 0, 0);
    unsigned short* pt = pbase + nt * 16;
    pt[0]      = f2bf(acc[0]);
    pt[ts]     = f2bf(acc[1]);
    pt[2 * ts] = f2bf(acc[2]);
    pt[3 * ts] = f2bf(acc[3]);
  }
}

// ---------------------------------------------------------------------------
// Block-local routing: block = (mod, b); 1024 threads = 32 groups of 32
// lanes (lane = n). Group g streams rows t in [g*nr, (g+1)*nr) contiguously.
// Per pass: logit = <Vc,p>, rc = softmax_32(logit) (no max-sub: |logit|<~2),
// acc += rc*p; LDS-atomic reduce; v = tanh(S); Vl += v (LDS) or store out.
// Audio blocks first (longest pole).
// ---------------------------------------------------------------------------
__global__ __launch_bounds__(1024) void route_kernel(
    const unsigned short* __restrict__ priAll, float* __restrict__ out) {
  __shared__ float Sl[544];  // [n][d] pitch 17, conflict-free
  __shared__ float Vl[512];

  int blk = blockIdx.x, tid = threadIdx.x;
  int b, T, obase;
  size_t poff;
  if (blk < 64)       { b = blk;       T = 512; poff = 4194304ull;  obase = 32768; }  // audio
  else if (blk < 128) { b = blk - 64;  T = 128; poff = 0;           obase = 0; }      // text
  else if (blk < 192) { b = blk - 128; T = 256; poff = 20971520ull; obase = 65536; }  // video
  else                { b = blk - 192; T = 256; poff = 29360128ull; obase = 98304; }  // frames

  int n = tid & 31, g = tid >> 5;
  int nr = T >> 5;  // rows per group: 16/4/8/8
  const unsigned short* pb =
      priAll + poff + ((size_t)b * T + (size_t)g * nr) * 512 + (size_t)n * 16;

  if (tid < 512) Vl[tid] = 0.f;

  for (int pass = 0; pass < 4; ++pass) {
    __syncthreads();  // prev tail (Sl reads, Vl writes) settled
    if (tid < 544) Sl[tid] = 0.f;
    float Vc[16];
    {
      const floatx4* vp = (const floatx4*)&Vl[n * 16];
      floatx4 v0 = vp[0], v1 = vp[1], v2 = vp[2], v3 = vp[3];
#pragma unroll
      for (int k = 0; k < 4; ++k) {
        Vc[k] = v0[k]; Vc[4 + k] = v1[k]; Vc[8 + k] = v2[k]; Vc[12 + k] = v3[k];
      }
    }
    __syncthreads();  // Sl zeroed before any atomics

    float acc[16];
#pragma unroll
    for (int d = 0; d < 16; ++d) acc[d] = 0.f;

    const uint4* q0 = (const uint4*)pb;
    uint4 c0 = q0[0], c1 = q0[1];
    for (int k = 0; k < nr; ++k) {
      uint4 n0, n1;
      if (k + 1 < nr) {
        const uint4* qn = (const uint4*)(pb + (size_t)(k + 1) * 512);
        n0 = qn[0];
        n1 = qn[1];
      }
      float p[16];
      {
        unsigned int wds[8] = {c0.x, c0.y, c0.z, c0.w, c1.x, c1.y, c1.z, c1.w};
#pragma unroll
        for (int kk = 0; kk < 8; ++kk) {
          union { unsigned int u; float f; } lo, hi;
          lo.u = wds[kk] << 16;
          hi.u = wds[kk] & 0xffff0000u;
          p[2 * kk] = lo.f;
          p[2 * kk + 1] = hi.f;
        }
      }
      float logit = 0.f;
#pragma unroll
      for (int d = 0; d < 16; ++d) logit += p[d] * Vc[d];
      float e = __expf(logit);  // |logit| <= ~2: no max-subtraction needed
      float s = e;
#pragma unroll
      for (int o = 16; o >= 1; o >>= 1) s += __shfl_xor(s, o, 32);
      float rc = e / s;
#pragma unroll
      for (int d = 0; d < 16; ++d) acc[d] += rc * p[d];
      c0 = n0;
      c1 = n1;
    }

#pragma unroll
    for (int d = 0; d < 16; ++d) atomicAdd(&Sl[n * 17 + d], acc[d]);
    __syncthreads();

    if (tid < 512) {
      float v = tanhf(Sl[(tid >> 4) * 17 + (tid & 15)]);
      if (pass == 3) out[obase + b * 512 + tid] = v;
      else Vl[tid] += v;
    }
  }
}

extern "C" void kernel_launch(void* const* d_in, const int* in_sizes, int n_in,
                              void* d_out, int out_size, void* d_ws, size_t ws_size,
                              hipStream_t stream) {
  const float* x0 = (const float*)d_in[0];
  const float* x1 = (const float*)d_in[1];
  const float* x2 = (const float*)d_in[2];
  const float* x3 = (const float*)d_in[3];
  const float* w0 = (const float*)d_in[4];
  const float* w1 = (const float*)d_in[5];
  const float* w2 = (const float*)d_in[6];
  const float* w3 = (const float*)d_in[7];

  unsigned short* pri = (unsigned short*)d_ws;

  pri_kernel<<<2304, 256, 0, stream>>>(x0, x1, x2, x3, w0, w1, w2, w3, pri);
  route_kernel<<<256, 1024, 0, stream>>>(pri, (float*)d_out);
}

// Round 8
// 313.148 us; speedup vs baseline: 3.1622x; 1.0268x over previous
//
#include <hip/hip_runtime.h>

// ---------------------------------------------------------------------------
// CapsuleSequenceToGraph, fp32 in/out. B=64, T={128,512,256,256}, n=32, d=16.
// Identity: b_k[b,t,n] = <Vcum_k[b,n,:], pri[b,t,n,:]>, Vcum_k = sum_{i<k} v_i.
//
// 2 dispatches. pri_kernel: R4-proven MFMA structure (76us), t-major
// [mod][t][b][n*16+d]. route_kernel: one block per (mod,b), 4 passes
// block-local (LDS Vcum/S); unroll-2 + prefetch-2 on the row stream; dummy
// dynamic LDS forces 1 block/CU so audio blocks own their CU.
// Lessons: ~25us/dependent-dispatch (R2-R4); grid.sync ~115us (R6); b-major
// 512KB-strided stores wreck pri (R7).
//
// ws: [0, 75497472) pri bf16 only.
// ---------------------------------------------------------------------------

typedef __attribute__((ext_vector_type(8))) short short8;
typedef __attribute__((ext_vector_type(4))) float floatx4;

static __device__ __forceinline__ unsigned short f2bf(float f) {
  union { float f; unsigned int i; } v;
  v.f = f;
  unsigned int x = v.i;
  return (unsigned short)((x + 0x7fffu + ((x >> 16) & 1u)) >> 16);  // RNE
}

// ---------------------------------------------------------------------------
// pri = x @ W per t, bf16 MFMA 16x16x32 (R4 structure, 76us measured).
// Block = (t, 16-n half): M=64(b) x N=256(nd) x K=64(j). Stores via per-wave
// LDS transpose -> coalesced dwordx4.
// ---------------------------------------------------------------------------
__global__ __launch_bounds__(256) void pri_kernel(
    const float* __restrict__ x0, const float* __restrict__ x1,
    const float* __restrict__ x2, const float* __restrict__ x3,
    const float* __restrict__ w0, const float* __restrict__ w1,
    const float* __restrict__ w2, const float* __restrict__ w3,
    unsigned short* __restrict__ priAll) {
  __shared__ unsigned short wb[256 * 72];   // [nd_local][j] bf16, pitch 72
  __shared__ unsigned short sc[4][16][136]; // per-wave store-transpose scratch

  int blk = blockIdx.x;
  int tid = threadIdx.x;

  int tpair = blk >> 1, half = blk & 1;
  const float* x;
  const float* W;
  unsigned short* priT;
  int T, t;
  if (tpair < 128)      { x = x0; W = w0; priT = priAll;               T = 128; t = tpair; }
  else if (tpair < 640) { x = x1; W = w1; priT = priAll + 4194304ull;  T = 512; t = tpair - 128; }
  else if (tpair < 896) { x = x2; W = w2; priT = priAll + 20971520ull; T = 256; t = tpair - 640; }
  else                  { x = x3; W = w3; priT = priAll + 29360128ull; T = 256; t = tpair - 896; }
  priT += (size_t)t * 32768;

  // ---- stage W[t, half*16 .. +16, :, :] -> wb[nd_local][j] bf16 ----
  {
    const floatx4* Wf4 = (const floatx4*)(W + (size_t)t * 32768);
    unsigned int* wb32 = (unsigned int*)wb;  // pitch 36 dwords
#pragma unroll
    for (int it = 0; it < 8; ++it) {
      int idx = it * 256 + tid;              // 0..2047
      int nl = idx >> 7, jp = (idx >> 2) & 31, dq = idx & 3;
      int ng = half * 16 + nl;
      floatx4 fa = Wf4[ng * 256 + (2 * jp) * 4 + dq];
      floatx4 fb = Wf4[ng * 256 + (2 * jp + 1) * 4 + dq];
      int rbase = nl * 16 + dq * 4;
#pragma unroll
      for (int k = 0; k < 4; ++k) {
        unsigned int dw = (unsigned int)f2bf(fa[k]) | ((unsigned int)f2bf(fb[k]) << 16);
        wb32[(rbase + k) * 36 + jp] = dw;
      }
    }
  }

  // ---- A fragments: x[b = mt*16+m][k = s*32 + q*8 + i] -> bf16 ----
  int lane = tid & 63, mt = tid >> 6;
  int m = lane & 15, q = lane >> 4;
  short8 afrag[2];
  {
    const float* xrow = x + ((size_t)(mt * 16 + m) * T + t) * 64;
#pragma unroll
    for (int s = 0; s < 2; ++s) {
      const floatx4* xp = (const floatx4*)(xrow + s * 32 + q * 8);
      floatx4 u0 = xp[0], u1 = xp[1];
      afrag[s][0] = (short)f2bf(u0[0]); afrag[s][1] = (short)f2bf(u0[1]);
      afrag[s][2] = (short)f2bf(u0[2]); afrag[s][3] = (short)f2bf(u0[3]);
      afrag[s][4] = (short)f2bf(u1[0]); afrag[s][5] = (short)f2bf(u1[1]);
      afrag[s][6] = (short)f2bf(u1[2]); afrag[s][7] = (short)f2bf(u1[3]);
    }
  }
  __syncthreads();

  // ---- 16 N-tiles; D layout: row b = mt*16+q*4+reg, col nd = nt*16+m ----
  // 8-tile groups through per-wave scratch (wave-private, no block sync).
  for (int g = 0; g < 2; ++g) {
#pragma unroll
    for (int k = 0; k < 8; ++k) {
      int nt = g * 8 + k;
      const short8* b0p = (const short8*)&wb[(nt * 16 + m) * 72 + q * 8];
      const short8* b1p = (const short8*)&wb[(nt * 16 + m) * 72 + 32 + q * 8];
      short8 bf0 = *b0p, bf1 = *b1p;
      floatx4 acc = {0.f, 0.f, 0.f, 0.f};
      acc = __builtin_amdgcn_mfma_f32_16x16x32_bf16(afrag[0], bf0, acc, 0, 0, 0);
      acc = __builtin_amdgcn_mfma_f32_16x16x32_bf16(afrag[1], bf1, acc, 0, 0, 0);
#pragma unroll
      for (int reg = 0; reg < 4; ++reg)
        sc[mt][q * 4 + reg][k * 16 + m] = f2bf(acc[reg]);
    }
#pragma unroll
    for (int i = 0; i < 4; ++i) {
      int bl = (lane >> 4) + i * 4;
      int sh = (lane & 15) * 8;
      short8 v = *(const short8*)&sc[mt][bl][sh];
      *(short8*)(priT + (size_t)(mt * 16 + bl) * 512 + half * 256 + g * 128 + sh) = v;
    }
  }
}

// ---------------------------------------------------------------------------
// Block-local routing: block = (mod, b); 1024 threads = 32 groups of 32
// lanes (lane = n). Group g streams rows t in [g*nr, (g+1)*nr); t-major
// layout -> row k at stride k*32768 shorts. Unroll-2, prefetch-2.
// 76KB dummy dynamic LDS -> 1 block/CU (audio blocks own their CU).
// ---------------------------------------------------------------------------
__global__ __launch_bounds__(1024) void route_kernel(
    const unsigned short* __restrict__ priAll, float* __restrict__ out) {
  __shared__ float Sl[544];  // [n][d] pitch 17, conflict-free
  __shared__ float Vl[512];
  extern __shared__ float occupancy_pad[];  // 76KB, forces 1 block/CU

  int blk = blockIdx.x, tid = threadIdx.x;
  if (out == nullptr) {  // never true; keeps pad observable
    occupancy_pad[tid] = 0.f;
    __syncthreads();
    Sl[0] = occupancy_pad[1023 - tid];
  }

  int b, T, obase;
  size_t poff;
  if (blk < 64)       { b = blk;       T = 512; poff = 4194304ull;  obase = 32768; }  // audio
  else if (blk < 128) { b = blk - 64;  T = 128; poff = 0;           obase = 0; }      // text
  else if (blk < 192) { b = blk - 128; T = 256; poff = 20971520ull; obase = 65536; }  // video
  else                { b = blk - 192; T = 256; poff = 29360128ull; obase = 98304; }  // frames

  int n = tid & 31, g = tid >> 5;
  int nr = T >> 5;  // rows per group: 16/4/8/8 (all even)
  const unsigned short* pb =
      priAll + poff + (size_t)(g * nr) * 32768 + (size_t)b * 512 + (size_t)n * 16;

  if (tid < 512) Vl[tid] = 0.f;

  for (int pass = 0; pass < 4; ++pass) {
    __syncthreads();  // prev pass tail (Sl reads, Vl writes) settled
    if (tid < 544) Sl[tid] = 0.f;
    float Vc[16];
    {
      const floatx4* vp = (const floatx4*)&Vl[n * 16];
      floatx4 v0 = vp[0], v1 = vp[1], v2 = vp[2], v3 = vp[3];
#pragma unroll
      for (int k = 0; k < 4; ++k) {
        Vc[k] = v0[k]; Vc[4 + k] = v1[k]; Vc[8 + k] = v2[k]; Vc[12 + k] = v3[k];
      }
    }
    __syncthreads();  // Sl zeroed before any atomics

    float acc[16];
#pragma unroll
    for (int d = 0; d < 16; ++d) acc[d] = 0.f;

    // prime 2 rows
    uint4 ca0, cb0, ca1, cb1;
    {
      const uint4* q0 = (const uint4*)pb;
      const uint4* q1 = (const uint4*)(pb + 32768);
      ca0 = q0[0]; cb0 = q0[1];
      ca1 = q1[0]; cb1 = q1[1];
    }
    for (int k = 0; k < nr; k += 2) {
      uint4 na0, nb0, na1, nb1;
      if (k + 2 < nr) {
        const uint4* q0 = (const uint4*)(pb + (size_t)(k + 2) * 32768);
        const uint4* q1 = (const uint4*)(pb + (size_t)(k + 3) * 32768);
        na0 = q0[0]; nb0 = q0[1];
        na1 = q1[0]; nb1 = q1[1];
      }
#pragma unroll
      for (int u = 0; u < 2; ++u) {
        uint4 ua = u ? ca1 : ca0;
        uint4 ub = u ? cb1 : cb0;
        float p[16];
        {
          unsigned int wds[8] = {ua.x, ua.y, ua.z, ua.w, ub.x, ub.y, ub.z, ub.w};
#pragma unroll
          for (int kk = 0; kk < 8; ++kk) {
            union { unsigned int u_; float f; } lo, hi;
            lo.u_ = wds[kk] << 16;
            hi.u_ = wds[kk] & 0xffff0000u;
            p[2 * kk] = lo.f;
            p[2 * kk + 1] = hi.f;
          }
        }
        float logit = 0.f;
#pragma unroll
        for (int d = 0; d < 16; ++d) logit += p[d] * Vc[d];
        float e = __expf(logit);  // |logit| <= ~2: safe without max-sub
        float s = e;
#pragma unroll
        for (int o = 16; o >= 1; o >>= 1) s += __shfl_xor(s, o, 32);
        float rc = e * __builtin_amdgcn_rcpf(s);
#pragma unroll
        for (int d = 0; d < 16; ++d) acc[d] += rc * p[d];
      }
      ca0 = na0; cb0 = nb0; ca1 = na1; cb1 = nb1;
    }

#pragma unroll
    for (int d = 0; d < 16; ++d) atomicAdd(&Sl[n * 17 + d], acc[d]);
    __syncthreads();

    if (tid < 512) {
      float v = tanhf(Sl[(tid >> 4) * 17 + (tid & 15)]);
      if (pass == 3) out[obase + b * 512 + tid] = v;
      else Vl[tid] += v;
    }
  }
}

extern "C" void kernel_launch(void* const* d_in, const int* in_sizes, int n_in,
                              void* d_out, int out_size, void* d_ws, size_t ws_size,
                              hipStream_t stream) {
  const float* x0 = (const float*)d_in[0];
  const float* x1 = (const float*)d_in[1];
  const float* x2 = (const float*)d_in[2];
  const float* x3 = (const float*)d_in[3];
  const float* w0 = (const float*)d_in[4];
  const float* w1 = (const float*)d_in[5];
  const float* w2 = (const float*)d_in[6];
  const float* w3 = (const float*)d_in[7];

  unsigned short* pri = (unsigned short*)d_ws;

  pri_kernel<<<2304, 256, 0, stream>>>(x0, x1, x2, x3, w0, w1, w2, w3, pri);
  route_kernel<<<256, 1024, 77824, stream>>>(pri, (float*)d_out);
}